// Round 5
// baseline (141.075 us; speedup 1.0000x reference)
//
#include <hip/hip_runtime.h>

typedef float vf2 __attribute__((ext_vector_type(2)));
typedef int   vi2 __attribute__((ext_vector_type(2)));

constexpr int BLK = 256;

struct F3 { float x, y, z; };
struct F4 { float x, y, z, w; };

__device__ __forceinline__ F3 cross3(const F3 a, const F3 b) {
    return { a.y * b.z - a.z * b.y,
             a.z * b.x - a.x * b.z,
             a.x * b.y - a.y * b.x };
}

// v + w*t + cross(qv, t), t = 2*cross(qv, v)   (matches _qrot)
__device__ __forceinline__ F3 qrot(const F4 q, const F3 v) {
    F3 qv{ q.x, q.y, q.z };
    F3 t = cross3(qv, v);
    t.x *= 2.f; t.y *= 2.f; t.z *= 2.f;
    F3 c = cross3(qv, t);
    return { v.x + q.w * t.x + c.x,
             v.y + q.w * t.y + c.y,
             v.z + q.w * t.z + c.z };
}

__device__ __forceinline__ F4 qmul(const F4 a, const F4 b) {
    return { a.w * b.x + a.x * b.w + a.y * b.z - a.z * b.y,
             a.w * b.y - a.x * b.z + a.y * b.w + a.z * b.x,
             a.w * b.z + a.x * b.y - a.y * b.x + a.z * b.w,
             a.w * b.w - a.x * b.x - a.y * b.y - a.z * b.z };
}

__global__ __launch_bounds__(BLK) void pose_graph_err_kernel(
    const float* __restrict__ nodes,   // [N_NODES, 7]
    const float* __restrict__ poses,   // [N_EDGES, 7]
    const int*   __restrict__ edges,   // [N_EDGES, 2] (int32)
    float*       __restrict__ out,     // [N_EDGES, 6]
    int n_edges)
{
    const long long e = (long long)blockIdx.x * BLK + threadIdx.x;
    if (e >= n_edges) return;

    // ---- independent streaming loads first (nt: don't pollute L2) ----
    const vi2 ij = __builtin_nontemporal_load((const vi2*)edges + e);

    float p[7];
    const float* pp = poses + e * 7;
    #pragma unroll
    for (int j = 0; j < 7; ++j) p[j] = __builtin_nontemporal_load(pp + j);

    // ---- node gathers (cached: 5.6 MB table, keep it hot in L2) ----
    const float* g1 = nodes + (size_t)ij.x * 7;
    const float* g2 = nodes + (size_t)ij.y * 7;
    float n1[7], n2[7];
    #pragma unroll
    for (int j = 0; j < 7; ++j) n1[j] = g1[j];
    #pragma unroll
    for (int j = 0; j < 7; ++j) n2[j] = g2[j];

    const F3 tp{ p[0], p[1], p[2] };
    const F4 qp{ p[3], p[4], p[5], p[6] };
    const F3 t1{ n1[0], n1[1], n1[2] };
    const F4 q1{ n1[3], n1[4], n1[5], n1[6] };
    const F3 t2{ n2[0], n2[1], n2[2] };
    const F4 q2{ n2[3], n2[4], n2[5], n2[6] };

    // inv(node1)
    const F4 qi{ -q1.x, -q1.y, -q1.z, q1.w };
    F3 ti = qrot(qi, t1);
    ti.x = -ti.x; ti.y = -ti.y; ti.z = -ti.z;

    // A = pose * inv(node1)
    const F3 ra = qrot(qp, ti);
    const F3 tA{ tp.x + ra.x, tp.y + ra.y, tp.z + ra.z };
    const F4 qA = qmul(qp, qi);

    // E = A * node2
    const F3 rb = qrot(qA, t2);
    const F3 tE{ tA.x + rb.x, tA.y + rb.y, tA.z + rb.z };
    F4 qE = qmul(qA, q2);

    // ---- se3_log (trig-free coef) ----
    const float sflip = (qE.w < 0.f) ? -1.f : 1.f;
    qE.x *= sflip; qE.y *= sflip; qE.z *= sflip; qE.w *= sflip;

    const float n2q = qE.x * qE.x + qE.y * qE.y + qE.z * qE.z;
    const float nq = sqrtf(n2q);
    const float theta = 2.f * atan2f(nq, qE.w);

    const float scale = (nq < 1e-6f) ? (2.f / fmaxf(qE.w, 1e-12f)) : (theta / nq);
    const F3 phi{ scale * qE.x, scale * qE.y, scale * qE.z };

    // theta = 2*atan2(n,w) => cos = (w^2-n^2)/s, sin = 2nw/s (s cancels):
    // (1+cos th)/(2 th sin th) == w/(2 th n)
    const float th2 = theta * theta;
    const float coef = (theta < 1e-4f)
        ? (1.f / 12.f + th2 / 720.f)
        : (1.f / th2 - qE.w / (2.f * theta * nq));

    const F3 pxt  = cross3(phi, tE);
    const F3 ppxt = cross3(phi, pxt);

    // ---- direct nt stores: 3 x 8B per lane, 8B-aligned (24B*t) ----
    vf2* ov = (vf2*)(out + e * 6);
    vf2 o0{ tE.x - 0.5f * pxt.x + coef * ppxt.x,
            tE.y - 0.5f * pxt.y + coef * ppxt.y };
    vf2 o1{ tE.z - 0.5f * pxt.z + coef * ppxt.z,
            phi.x };
    vf2 o2{ phi.y, phi.z };
    __builtin_nontemporal_store(o0, ov + 0);
    __builtin_nontemporal_store(o1, ov + 1);
    __builtin_nontemporal_store(o2, ov + 2);
}

extern "C" void kernel_launch(void* const* d_in, const int* in_sizes, int n_in,
                              void* d_out, int out_size, void* d_ws, size_t ws_size,
                              hipStream_t stream) {
    const float* nodes = (const float*)d_in[0];
    const float* poses = (const float*)d_in[1];
    const int*   edges = (const int*)d_in[2];
    float* out = (float*)d_out;

    const int n_edges = in_sizes[2] / 2;
    const int nblocks = (n_edges + BLK - 1) / BLK;
    pose_graph_err_kernel<<<nblocks, BLK, 0, stream>>>(nodes, poses, edges, out, n_edges);
}

// Round 8
// 118.548 us; speedup vs baseline: 1.1900x; 1.1900x over previous
//
#include <hip/hip_runtime.h>

typedef int   vi2 __attribute__((ext_vector_type(2)));
typedef float vf2 __attribute__((ext_vector_type(2)));
typedef float vf4 __attribute__((ext_vector_type(4)));

constexpr int BLK = 256;

struct F3 { float x, y, z; };
struct F4 { float x, y, z, w; };

__device__ __forceinline__ F3 cross3(const F3 a, const F3 b) {
    return { a.y * b.z - a.z * b.y,
             a.z * b.x - a.x * b.z,
             a.x * b.y - a.y * b.x };
}

// v + w*t + cross(qv, t), t = 2*cross(qv, v)   (matches _qrot)
__device__ __forceinline__ F3 qrot(const F4 q, const F3 v) {
    F3 qv{ q.x, q.y, q.z };
    F3 t = cross3(qv, v);
    t.x *= 2.f; t.y *= 2.f; t.z *= 2.f;
    F3 c = cross3(qv, t);
    return { v.x + q.w * t.x + c.x,
             v.y + q.w * t.y + c.y,
             v.z + q.w * t.z + c.z };
}

__device__ __forceinline__ F4 qmul(const F4 a, const F4 b) {
    return { a.w * b.x + a.x * b.w + a.y * b.z - a.z * b.y,
             a.w * b.y - a.x * b.z + a.y * b.w + a.z * b.x,
             a.w * b.z + a.x * b.y - a.y * b.x + a.z * b.w,
             a.w * b.w - a.x * b.x - a.y * b.y - a.z * b.z };
}

__global__ __launch_bounds__(BLK) void pose_graph_err_kernel(
    const float* __restrict__ nodes,   // [N_NODES, 7] fp32 (must stay fp32: log-map
                                       // discontinuity at theta=pi makes any node
                                       // quantization flip sign(qE.w) on tail edges)
    const float* __restrict__ poses,   // [N_EDGES, 7]
    const int*   __restrict__ edges,   // [N_EDGES, 2] (int32)
    float*       __restrict__ out,     // [N_EDGES, 6]
    int n_edges)
{
    __shared__ float s_pose[BLK * 7];  // 7168 B

    const int tid = threadIdx.x;
    const int bstart = blockIdx.x * BLK;
    const int cnt = min(BLK, n_edges - bstart);

    // ---- node gathers first (longest latency; keep them in flight) ----
    F3 t1, t2; F4 q1, q2;
    if (tid < cnt) {
        const vi2 ij = __builtin_nontemporal_load((const vi2*)edges + (bstart + tid));
        const float* g1 = nodes + (size_t)ij.x * 7;
        const float* g2 = nodes + (size_t)ij.y * 7;
        t1 = { g1[0], g1[1], g1[2] };
        q1 = { g1[3], g1[4], g1[5], g1[6] };
        t2 = { g2[0], g2[1], g2[2] };
        q2 = { g2[3], g2[4], g2[5], g2[6] };
    }

    // ---- stage poses coalesced, non-temporal (don't evict node table from L2) ----
    if (cnt == BLK) {
        const vf4* pv = (const vf4*)(poses + (size_t)bstart * 7);
        vf4* sp = (vf4*)s_pose;
        #pragma unroll
        for (int i = tid; i < BLK * 7 / 4; i += BLK)
            sp[i] = __builtin_nontemporal_load(pv + i);
    } else {
        for (int i = tid; i < cnt * 7; i += BLK)
            s_pose[i] = poses[(size_t)bstart * 7 + i];
    }
    __syncthreads();

    if (tid >= cnt) return;

    // stride-7 LDS reads: gcd(7,32)=1 -> conflict-free
    const float* sp = s_pose + tid * 7;
    const F3 tp{ sp[0], sp[1], sp[2] };
    const F4 qp{ sp[3], sp[4], sp[5], sp[6] };

    // inv(node1)
    const F4 qi{ -q1.x, -q1.y, -q1.z, q1.w };
    F3 ti = qrot(qi, t1);
    ti.x = -ti.x; ti.y = -ti.y; ti.z = -ti.z;

    // A = pose * inv(node1)
    const F3 ra = qrot(qp, ti);
    const F3 tA{ tp.x + ra.x, tp.y + ra.y, tp.z + ra.z };
    const F4 qA = qmul(qp, qi);

    // E = A * node2
    const F3 rb = qrot(qA, t2);
    const F3 tE{ tA.x + rb.x, tA.y + rb.y, tA.z + rb.z };
    F4 qE = qmul(qA, q2);

    // ---- se3_log (trig-free coef) ----
    const float sflip = (qE.w < 0.f) ? -1.f : 1.f;
    qE.x *= sflip; qE.y *= sflip; qE.z *= sflip; qE.w *= sflip;

    const float n2q = qE.x * qE.x + qE.y * qE.y + qE.z * qE.z;
    const float nq = sqrtf(n2q);
    const float theta = 2.f * atan2f(nq, qE.w);

    const float scale = (nq < 1e-6f) ? (2.f / fmaxf(qE.w, 1e-12f)) : (theta / nq);
    const F3 phi{ scale * qE.x, scale * qE.y, scale * qE.z };

    // theta = 2*atan2(n,w) => cos = (w^2-n^2)/s, sin = 2nw/s (s cancels):
    // (1+cos th)/(2 th sin th) == w/(2 th n), exactly.
    const float th2 = theta * theta;
    const float coef = (theta < 1e-4f)
        ? (1.f / 12.f + th2 / 720.f)
        : (1.f / th2 - qE.w / (2.f * theta * nq));

    const F3 pxt  = cross3(phi, tE);
    const F3 ppxt = cross3(phi, pxt);

    // ---- direct nt stores: 3 x 8B per lane; wave covers 1536B contiguous ----
    vf2* ov = (vf2*)(out + (size_t)(bstart + tid) * 6);
    vf2 o0{ tE.x - 0.5f * pxt.x + coef * ppxt.x,
            tE.y - 0.5f * pxt.y + coef * ppxt.y };
    vf2 o1{ tE.z - 0.5f * pxt.z + coef * ppxt.z,
            phi.x };
    vf2 o2{ phi.y, phi.z };
    __builtin_nontemporal_store(o0, ov + 0);
    __builtin_nontemporal_store(o1, ov + 1);
    __builtin_nontemporal_store(o2, ov + 2);
}

extern "C" void kernel_launch(void* const* d_in, const int* in_sizes, int n_in,
                              void* d_out, int out_size, void* d_ws, size_t ws_size,
                              hipStream_t stream) {
    const float* nodes = (const float*)d_in[0];
    const float* poses = (const float*)d_in[1];
    const int*   edges = (const int*)d_in[2];
    float* out = (float*)d_out;

    const int n_edges = in_sizes[2] / 2;
    const int nblocks = (n_edges + BLK - 1) / BLK;
    pose_graph_err_kernel<<<nblocks, BLK, 0, stream>>>(nodes, poses, edges, out, n_edges);
}

// Round 9
// 115.377 us; speedup vs baseline: 1.2227x; 1.0275x over previous
//
#include <hip/hip_runtime.h>

typedef int   vi2 __attribute__((ext_vector_type(2)));
typedef float vf4 __attribute__((ext_vector_type(4)));

constexpr int BLK = 256;

struct F3 { float x, y, z; };
struct F4 { float x, y, z, w; };

__device__ __forceinline__ F3 cross3(const F3 a, const F3 b) {
    return { a.y * b.z - a.z * b.y,
             a.z * b.x - a.x * b.z,
             a.x * b.y - a.y * b.x };
}

// v + w*t + cross(qv, t), t = 2*cross(qv, v)   (matches _qrot)
__device__ __forceinline__ F3 qrot(const F4 q, const F3 v) {
    F3 qv{ q.x, q.y, q.z };
    F3 t = cross3(qv, v);
    t.x *= 2.f; t.y *= 2.f; t.z *= 2.f;
    F3 c = cross3(qv, t);
    return { v.x + q.w * t.x + c.x,
             v.y + q.w * t.y + c.y,
             v.z + q.w * t.z + c.z };
}

__device__ __forceinline__ F4 qmul(const F4 a, const F4 b) {
    return { a.w * b.x + a.x * b.w + a.y * b.z - a.z * b.y,
             a.w * b.y - a.x * b.z + a.y * b.w + a.z * b.x,
             a.w * b.z + a.x * b.y - a.y * b.x + a.z * b.w,
             a.w * b.w - a.x * b.x - a.y * b.y - a.z * b.z };
}

__global__ __launch_bounds__(BLK) void pose_graph_err_kernel(
    const float* __restrict__ nodes,   // [N_NODES, 7] fp32 (must stay fp32: log-map
                                       // discontinuity at theta=pi; quantization flips
                                       // sign(qE.w) on tail edges -> 2pi jumps)
    const float* __restrict__ poses,   // [N_EDGES, 7]
    const int*   __restrict__ edges,   // [N_EDGES, 2] (int32)
    float*       __restrict__ out,     // [N_EDGES, 6]
    int n_edges)
{
    __shared__ float s_pose[BLK * 7];  // 7168 B
    __shared__ float s_out [BLK * 6];  // 6144 B

    const int tid = threadIdx.x;
    const int bstart = blockIdx.x * BLK;
    const int cnt = min(BLK, n_edges - bstart);

    // ---- node gathers first (longest latency; issue before staging) ----
    F3 t1, t2; F4 q1, q2;
    if (tid < cnt) {
        const vi2 ij = __builtin_nontemporal_load((const vi2*)edges + (bstart + tid));
        const float* g1 = nodes + (size_t)ij.x * 7;
        const float* g2 = nodes + (size_t)ij.y * 7;
        t1 = { g1[0], g1[1], g1[2] };
        q1 = { g1[3], g1[4], g1[5], g1[6] };
        t2 = { g2[0], g2[1], g2[2] };
        q2 = { g2[3], g2[4], g2[5], g2[6] };
    }

    // ---- stage poses coalesced, nt loads (don't evict node table from L2) ----
    if (cnt == BLK) {
        const vf4* pv = (const vf4*)(poses + (size_t)bstart * 7);
        vf4* sp = (vf4*)s_pose;
        #pragma unroll
        for (int i = tid; i < BLK * 7 / 4; i += BLK)
            sp[i] = __builtin_nontemporal_load(pv + i);
    } else {
        for (int i = tid; i < cnt * 7; i += BLK)
            s_pose[i] = poses[(size_t)bstart * 7 + i];
    }
    __syncthreads();

    if (tid < cnt) {
        // stride-7 LDS reads: gcd(7,32)=1 -> conflict-free
        const float* sp = s_pose + tid * 7;
        const F3 tp{ sp[0], sp[1], sp[2] };
        const F4 qp{ sp[3], sp[4], sp[5], sp[6] };

        // inv(node1)
        const F4 qi{ -q1.x, -q1.y, -q1.z, q1.w };
        F3 ti = qrot(qi, t1);
        ti.x = -ti.x; ti.y = -ti.y; ti.z = -ti.z;

        // A = pose * inv(node1)
        const F3 ra = qrot(qp, ti);
        const F3 tA{ tp.x + ra.x, tp.y + ra.y, tp.z + ra.z };
        const F4 qA = qmul(qp, qi);

        // E = A * node2
        const F3 rb = qrot(qA, t2);
        const F3 tE{ tA.x + rb.x, tA.y + rb.y, tA.z + rb.z };
        F4 qE = qmul(qA, q2);

        // ---- se3_log (trig-free coef) ----
        const float sflip = (qE.w < 0.f) ? -1.f : 1.f;
        qE.x *= sflip; qE.y *= sflip; qE.z *= sflip; qE.w *= sflip;

        const float n2q = qE.x * qE.x + qE.y * qE.y + qE.z * qE.z;
        const float nq = sqrtf(n2q);
        const float theta = 2.f * atan2f(nq, qE.w);

        const float scale = (nq < 1e-6f) ? (2.f / fmaxf(qE.w, 1e-12f)) : (theta / nq);
        const F3 phi{ scale * qE.x, scale * qE.y, scale * qE.z };

        // theta = 2*atan2(n,w) => cos = (w^2-n^2)/s, sin = 2nw/s (s cancels):
        // (1+cos th)/(2 th sin th) == w/(2 th n), exactly.
        const float th2 = theta * theta;
        const float coef = (theta < 1e-4f)
            ? (1.f / 12.f + th2 / 720.f)
            : (1.f / th2 - qE.w / (2.f * theta * nq));

        const F3 pxt  = cross3(phi, tE);
        const F3 ppxt = cross3(phi, pxt);

        float* so = s_out + tid * 6;
        so[0] = tE.x - 0.5f * pxt.x + coef * ppxt.x;
        so[1] = tE.y - 0.5f * pxt.y + coef * ppxt.y;
        so[2] = tE.z - 0.5f * pxt.z + coef * ppxt.z;
        so[3] = phi.x; so[4] = phi.y; so[5] = phi.z;
    }
    __syncthreads();

    // ---- coalesced full-line vf4 stores through L2 (replay-friendly) ----
    if (cnt == BLK) {
        vf4* ov = (vf4*)(out + (size_t)bstart * 6);
        const vf4* sv = (const vf4*)s_out;
        #pragma unroll
        for (int i = tid; i < BLK * 6 / 4; i += BLK) ov[i] = sv[i];
    } else {
        for (int i = tid; i < cnt * 6; i += BLK)
            out[(size_t)bstart * 6 + i] = s_out[i];
    }
}

extern "C" void kernel_launch(void* const* d_in, const int* in_sizes, int n_in,
                              void* d_out, int out_size, void* d_ws, size_t ws_size,
                              hipStream_t stream) {
    const float* nodes = (const float*)d_in[0];
    const float* poses = (const float*)d_in[1];
    const int*   edges = (const int*)d_in[2];
    float* out = (float*)d_out;

    const int n_edges = in_sizes[2] / 2;
    const int nblocks = (n_edges + BLK - 1) / BLK;
    pose_graph_err_kernel<<<nblocks, BLK, 0, stream>>>(nodes, poses, edges, out, n_edges);
}